// Round 20
// baseline (88.759 us; speedup 1.0000x reference)
//
#include <hip/hip_runtime.h>
#include <hip/hip_fp16.h>

#define DIM 256
#define NC 16
#define NG 1000
#define CHUNK 6256      // div by 16: aligned int4 streams; 512*6256 >= 3.2M
#define NBLK 512
#define FT 1024

typedef _Float16 f16x8 __attribute__((ext_vector_type(8)));
typedef float f32x4 __attribute__((ext_vector_type(4)));

// ---------------------------------------------------------------------------
// K1: hidden = x @ W + b via MFMA (r11, unchanged; ~15 us).
// ---------------------------------------------------------------------------
__global__ void __launch_bounds__(256) hidden_kernel(
    const float* __restrict__ x, const float* __restrict__ W,
    const float* __restrict__ b, __half* __restrict__ hidden, int N) {
    const int lane = threadIdx.x & 63;
    const int wave = (blockIdx.x * blockDim.x + threadIdx.x) >> 6;
    const int m = lane & 15;
    const int kb = lane >> 4;

    const int nTiles = (N + 15) >> 4;
    if (wave >= nTiles) return;

    f16x8 wf[8];
#pragma unroll
    for (int s = 0; s < 8; ++s) {
        const float* wp = W + (size_t)(s * 32 + kb * 8) * NC + m;
        wf[s] = (f16x8){(_Float16)wp[0 * NC], (_Float16)wp[1 * NC],
                        (_Float16)wp[2 * NC], (_Float16)wp[3 * NC],
                        (_Float16)wp[4 * NC], (_Float16)wp[5 * NC],
                        (_Float16)wp[6 * NC], (_Float16)wp[7 * NC]};
    }
    const float bias = b[m];

    const int node0 = wave * 16;
    const int row = min(node0 + m, N - 1);
    const float* xp = x + (size_t)row * DIM + kb * 8;

    float4 ra[8], rb[8];
#pragma unroll
    for (int s = 0; s < 8; ++s) {
        ra[s] = *(const float4*)(xp + s * 32);
        rb[s] = *(const float4*)(xp + s * 32 + 4);
    }

    f32x4 acc = {0.f, 0.f, 0.f, 0.f};
#pragma unroll
    for (int s = 0; s < 8; ++s) {
        f16x8 af = (f16x8){(_Float16)ra[s].x, (_Float16)ra[s].y,
                           (_Float16)ra[s].z, (_Float16)ra[s].w,
                           (_Float16)rb[s].x, (_Float16)rb[s].y,
                           (_Float16)rb[s].z, (_Float16)rb[s].w};
        acc = __builtin_amdgcn_mfma_f32_16x16x32_f16(af, wf[s], acc, 0, 0, 0);
    }

#pragma unroll
    for (int j = 0; j < 4; ++j) {
        int node = node0 + kb * 4 + j;
        if (node < N)
            hidden[(size_t)node * NC + m] = __float2half(acc[j] + bias);
    }
}

// ---------------------------------------------------------------------------
// K2: node -> graph id as u16 (searchsorted 'right')
// ---------------------------------------------------------------------------
__global__ void seg_kernel(const int* __restrict__ ed_idx,
                           unsigned short* __restrict__ node_seg, int N, int G) {
    int n = blockIdx.x * blockDim.x + threadIdx.x;
    if (n >= N) return;
    int lo = 0, hi = G;
    while (lo < hi) {
        int mid = (lo + hi) >> 1;
        if (ed_idx[mid] <= n) lo = mid + 1; else hi = mid;
    }
    node_seg[n] = (unsigned short)lo;
}

// ---------------------------------------------------------------------------
// K3: fused sort + pool. Sort: int4/float4-vectorized streams (r19).
// Pool (NEW): lane-owns-edge. Each quad still owns one graph (dynamic
// queue), but lane q processes edges i+q, i+4+q of the run with FULL 32B
// hidden rows (2 x b128) -> per quad-iteration 8 edges on 16 outstanding
// requests, vs r17's 4 edges on 16 (2x edge throughput at equal request
// pressure). acc[16] f32 per lane; 2-level quad shfl-reduce at graph end;
// lane q writes channels 4q..4q+3 of the partial slice.
// ---------------------------------------------------------------------------
__global__ void __launch_bounds__(FT) gcn_pool_kernel(
    const int* __restrict__ rows, const int* __restrict__ cols,
    const float* __restrict__ vals, const __half* __restrict__ hidden,
    const unsigned short* __restrict__ node_seg,
    float* __restrict__ partials, int nE) {
    __shared__ unsigned hist[NG];
    __shared__ unsigned cursor[NG];
    __shared__ unsigned wsum[FT / 64];
    __shared__ unsigned wctr;
    __shared__ unsigned short raw_g[CHUNK];
    __shared__ uint2 sorted[CHUNK];

    const int t = threadIdx.x, lane = t & 63, wid = t >> 6;
    const int beg = blockIdx.x * CHUNK;
    const int cnt = min(nE - beg, CHUNK);

    for (int i = t; i < NG; i += FT) hist[i] = 0u;
    if (t == 0) wctr = 0u;
    __syncthreads();

    // ---- pass A: int4 rows stream + 4x u16 seg gather + hist atomic ----
    for (int i = t * 4; i < cnt; i += FT * 4) {
        if (i + 3 < cnt) {
            int4 r4 = *(const int4*)(rows + beg + i);
            unsigned g0 = node_seg[r4.x];
            unsigned g1 = node_seg[r4.y];
            unsigned g2 = node_seg[r4.z];
            unsigned g3 = node_seg[r4.w];
            ushort4 gw;
            gw.x = (unsigned short)g0; gw.y = (unsigned short)g1;
            gw.z = (unsigned short)g2; gw.w = (unsigned short)g3;
            *(ushort4*)(raw_g + i) = gw;
            if (g0 < NG) atomicAdd(&hist[g0], 1u);
            if (g1 < NG) atomicAdd(&hist[g1], 1u);
            if (g2 < NG) atomicAdd(&hist[g2], 1u);
            if (g3 < NG) atomicAdd(&hist[g3], 1u);
        } else {
            for (int j = i; j < cnt; ++j) {
                unsigned g = node_seg[rows[beg + j]];
                raw_g[j] = (unsigned short)g;
                if (g < NG) atomicAdd(&hist[g], 1u);
            }
        }
    }
    __syncthreads();

    // ---- block-wide exclusive scan of hist[0..NG) -> cursor ----
    unsigned v = (t < NG) ? hist[t] : 0u;
    unsigned inc = v;
#pragma unroll
    for (int d = 1; d < 64; d <<= 1) {
        unsigned u = __shfl_up(inc, d);
        if (lane >= d) inc += u;
    }
    if (lane == 63) wsum[wid] = inc;
    __syncthreads();
    if (wid == 0) {
        unsigned v2 = (lane < FT / 64) ? wsum[lane] : 0u;
        unsigned inc2 = v2;
#pragma unroll
        for (int d = 1; d < FT / 64; d <<= 1) {
            unsigned u = __shfl_up(inc2, d);
            if (lane >= d) inc2 += u;
        }
        if (lane < FT / 64) wsum[lane] = inc2 - v2;
    }
    __syncthreads();
    if (t < NG) cursor[t] = wsum[wid] + inc - v;
    __syncthreads();

    // ---- pass B: int4 cols + float4 vals streams + LDS scatter ----
    for (int i = t * 4; i < cnt; i += FT * 4) {
        if (i + 3 < cnt) {
            int4 c4 = *(const int4*)(cols + beg + i);
            float4 v4 = *(const float4*)(vals + beg + i);
            ushort4 gw = *(const ushort4*)(raw_g + i);
            if (gw.x < NG) sorted[atomicAdd(&cursor[gw.x], 1u)] =
                make_uint2((unsigned)c4.x, __float_as_uint(v4.x));
            if (gw.y < NG) sorted[atomicAdd(&cursor[gw.y], 1u)] =
                make_uint2((unsigned)c4.y, __float_as_uint(v4.y));
            if (gw.z < NG) sorted[atomicAdd(&cursor[gw.z], 1u)] =
                make_uint2((unsigned)c4.z, __float_as_uint(v4.z));
            if (gw.w < NG) sorted[atomicAdd(&cursor[gw.w], 1u)] =
                make_uint2((unsigned)c4.w, __float_as_uint(v4.w));
        } else {
            for (int j = i; j < cnt; ++j) {
                unsigned g = raw_g[j];
                if (g < NG) sorted[atomicAdd(&cursor[g], 1u)] =
                    make_uint2((unsigned)cols[beg + j],
                               __float_as_uint(vals[beg + j]));
            }
        }
    }
    __syncthreads();
    // post-B: cursor[g] = run end; run start = cursor[g] - hist[g]

    // ---- pool: quads pop graphs; lane owns edges (full 32B rows) ----
    const int q = lane & 3;
    unsigned g;
    if (q == 0) g = atomicAdd(&wctr, 1u);
    g = (unsigned)__shfl((int)g, lane & ~3);
    while (g < NG) {
        float acc[NC];
#pragma unroll
        for (int c = 0; c < NC; ++c) acc[c] = 0.f;

        unsigned cg = hist[g];
        if (cg) {
            unsigned rend = cursor[g];
            unsigned rbeg = rend - cg;
            unsigned last = rend - 1;
            for (unsigned i = rbeg; i < rend; i += 8) {
                unsigned e0 = min(i + q, last);
                unsigned e1 = min(i + 4 + q, last);
                uint2 c0 = sorted[e0], c1 = sorted[e1];
                const uint4* p0 = (const uint4*)(hidden + (size_t)c0.x * NC);
                const uint4* p1 = (const uint4*)(hidden + (size_t)c1.x * NC);
                uint4 h00 = p0[0], h01 = p0[1];
                uint4 h10 = p1[0], h11 = p1[1];
                float v0 = (i + q < rend) ? __uint_as_float(c0.y) : 0.f;
                float v1 = (i + 4 + q < rend) ? __uint_as_float(c1.y) : 0.f;

                const __half2* a0 = (const __half2*)&h00;
                const __half2* a1 = (const __half2*)&h01;
                const __half2* b0 = (const __half2*)&h10;
                const __half2* b1 = (const __half2*)&h11;
#pragma unroll
                for (int k = 0; k < 4; ++k) {
                    float2 f0 = __half22float2(a0[k]);
                    float2 f1 = __half22float2(a1[k]);
                    acc[2 * k]         = fmaf(v0, f0.x, acc[2 * k]);
                    acc[2 * k + 1]     = fmaf(v0, f0.y, acc[2 * k + 1]);
                    acc[8 + 2 * k]     = fmaf(v0, f1.x, acc[8 + 2 * k]);
                    acc[8 + 2 * k + 1] = fmaf(v0, f1.y, acc[8 + 2 * k + 1]);
                    float2 g0 = __half22float2(b0[k]);
                    float2 g1 = __half22float2(b1[k]);
                    acc[2 * k]         = fmaf(v1, g0.x, acc[2 * k]);
                    acc[2 * k + 1]     = fmaf(v1, g0.y, acc[2 * k + 1]);
                    acc[8 + 2 * k]     = fmaf(v1, g1.x, acc[8 + 2 * k]);
                    acc[8 + 2 * k + 1] = fmaf(v1, g1.y, acc[8 + 2 * k + 1]);
                }
            }
        }

        // quad reduce: sum the 4 lanes' edge-subsets (shfl_xor 1, then 2)
#pragma unroll
        for (int c = 0; c < NC; ++c) {
            acc[c] += __shfl_xor(acc[c], 1);
            acc[c] += __shfl_xor(acc[c], 2);
        }
        // lane q writes channels 4q..4q+3
        {
            const int c0 = q * 4;
            float4* p4 = (float4*)(partials +
                                   ((size_t)blockIdx.x * NG + g) * NC + c0);
            *p4 = make_float4(acc[c0], acc[c0 + 1], acc[c0 + 2], acc[c0 + 3]);
        }

        if (q == 0) g = atomicAdd(&wctr, 1u);
        g = (unsigned)__shfl((int)g, lane & ~3);
    }
}

// ---------------------------------------------------------------------------
// K4: fold partials[NBLK][NG*NC] into out; blockIdx.y picks 64 slices.
// ---------------------------------------------------------------------------
__global__ void reduce_kernel(const float* __restrict__ partials,
                              float* __restrict__ out) {
    int i = blockIdx.x * blockDim.x + threadIdx.x;
    if (i >= NG * NC) return;
    const int per = NBLK / 8;  // 64
    const float* p = partials + (size_t)(blockIdx.y * per) * (NG * NC) + i;
    float s0 = 0.f, s1 = 0.f, s2 = 0.f, s3 = 0.f;
#pragma unroll 4
    for (int k = 0; k < per; k += 4) {
        s0 += p[(size_t)(k + 0) * (NG * NC)];
        s1 += p[(size_t)(k + 1) * (NG * NC)];
        s2 += p[(size_t)(k + 2) * (NG * NC)];
        s3 += p[(size_t)(k + 3) * (NG * NC)];
    }
    atomicAdd(&out[i], (s0 + s1) + (s2 + s3));
}

extern "C" void kernel_launch(void* const* d_in, const int* in_sizes, int n_in,
                              void* d_out, int out_size, void* d_ws, size_t ws_size,
                              hipStream_t stream) {
    const float* x      = (const float*)d_in[0];
    const int*   ed_idx = (const int*)  d_in[1];
    const int*   rows   = (const int*)  d_in[2];
    const int*   cols   = (const int*)  d_in[3];
    const float* vals   = (const float*)d_in[4];
    const float* W      = (const float*)d_in[5];
    const float* b      = (const float*)d_in[6];
    float* out = (float*)d_out;

    int N  = in_sizes[0] / DIM;   // 100000
    int G  = in_sizes[1];         // 1000
    int nE = in_sizes[2];         // 3200000

    size_t off = 0;
    auto alloc = [&](size_t bytes, size_t align) {
        off = (off + align - 1) / align * align;
        size_t r = off; off += bytes; return r;
    };
    __half* hidden = (__half*)((char*)d_ws + alloc((size_t)N * NC * 2, 16));
    unsigned short* node_seg =
        (unsigned short*)((char*)d_ws + alloc((size_t)N * 2, 16));
    float* partials =
        (float*)((char*)d_ws + alloc((size_t)NBLK * NG * NC * 4, 16));
    (void)ws_size;

    (void)hipMemsetAsync(d_out, 0, (size_t)out_size * sizeof(float), stream);

    seg_kernel<<<(N + 255) / 256, 256, 0, stream>>>(ed_idx, node_seg, N, G);
    int nTiles = (N + 15) / 16;
    int hblocks = (nTiles + 3) / 4;
    hidden_kernel<<<hblocks, 256, 0, stream>>>(x, W, b, hidden, N);
    gcn_pool_kernel<<<NBLK, FT, 0, stream>>>(rows, cols, vals, hidden,
                                             node_seg, partials, nE);
    dim3 rg((NG * NC + 255) / 256, 8);
    reduce_kernel<<<rg, 256, 0, stream>>>(partials, out);
}

// Round 21
// 80.802 us; speedup vs baseline: 1.0985x; 1.0985x over previous
//
#include <hip/hip_runtime.h>
#include <hip/hip_fp16.h>

#define DIM 256
#define NC 16
#define NG 1000
#define CHUNK 6256      // div by 16: aligned int4 streams; 512*6256 >= 3.2M
#define NBLK 512
#define FT 1024

typedef _Float16 f16x8 __attribute__((ext_vector_type(8)));
typedef float f32x4 __attribute__((ext_vector_type(4)));

// ---------------------------------------------------------------------------
// K1: hidden = x @ W + b via MFMA (~16 us, near the 16.3 us x-read floor).
// One wave per 16-node tile, K=256 as 8 x mfma_f32_16x16x32_f16; W in 32
// VGPRs of B-fragments (loaded once, L2-broadcast); zero LDS, zero barriers.
// ---------------------------------------------------------------------------
__global__ void __launch_bounds__(256) hidden_kernel(
    const float* __restrict__ x, const float* __restrict__ W,
    const float* __restrict__ b, __half* __restrict__ hidden, int N) {
    const int lane = threadIdx.x & 63;
    const int wave = (blockIdx.x * blockDim.x + threadIdx.x) >> 6;
    const int m = lane & 15;
    const int kb = lane >> 4;

    const int nTiles = (N + 15) >> 4;
    if (wave >= nTiles) return;

    f16x8 wf[8];
#pragma unroll
    for (int s = 0; s < 8; ++s) {
        const float* wp = W + (size_t)(s * 32 + kb * 8) * NC + m;
        wf[s] = (f16x8){(_Float16)wp[0 * NC], (_Float16)wp[1 * NC],
                        (_Float16)wp[2 * NC], (_Float16)wp[3 * NC],
                        (_Float16)wp[4 * NC], (_Float16)wp[5 * NC],
                        (_Float16)wp[6 * NC], (_Float16)wp[7 * NC]};
    }
    const float bias = b[m];

    const int node0 = wave * 16;
    const int row = min(node0 + m, N - 1);
    const float* xp = x + (size_t)row * DIM + kb * 8;

    float4 ra[8], rb[8];
#pragma unroll
    for (int s = 0; s < 8; ++s) {
        ra[s] = *(const float4*)(xp + s * 32);
        rb[s] = *(const float4*)(xp + s * 32 + 4);
    }

    f32x4 acc = {0.f, 0.f, 0.f, 0.f};
#pragma unroll
    for (int s = 0; s < 8; ++s) {
        f16x8 af = (f16x8){(_Float16)ra[s].x, (_Float16)ra[s].y,
                           (_Float16)ra[s].z, (_Float16)ra[s].w,
                           (_Float16)rb[s].x, (_Float16)rb[s].y,
                           (_Float16)rb[s].z, (_Float16)rb[s].w};
        acc = __builtin_amdgcn_mfma_f32_16x16x32_f16(af, wf[s], acc, 0, 0, 0);
    }

#pragma unroll
    for (int j = 0; j < 4; ++j) {
        int node = node0 + kb * 4 + j;
        if (node < N)
            hidden[(size_t)node * NC + m] = __float2half(acc[j] + bias);
    }
}

// ---------------------------------------------------------------------------
// K2: node -> graph id as u16 (searchsorted 'right')
// ---------------------------------------------------------------------------
__global__ void seg_kernel(const int* __restrict__ ed_idx,
                           unsigned short* __restrict__ node_seg, int N, int G) {
    int n = blockIdx.x * blockDim.x + threadIdx.x;
    if (n >= N) return;
    int lo = 0, hi = G;
    while (lo < hi) {
        int mid = (lo + hi) >> 1;
        if (ed_idx[mid] <= n) lo = mid + 1; else hi = mid;
    }
    node_seg[n] = (unsigned short)lo;
}

// ---------------------------------------------------------------------------
// K3: fused sort + quad-channel pool (round-19 optimum).
//   Sort: int4/float4-vectorized streams (4 edges/thread/iter), ushort4
//         raw_g stores, in-LDS counting sort.
//   Pool: quads pull graphs from a dynamic LDS queue (balanced); per group
//         4 independent LDS reads + 4 independent 8B gathers (MLP=4, the
//         measured optimum of the latency-depth axis); quad-coalesced
//         same-row reads (4 lanes share each 32B row -> L1 merge).
// ---------------------------------------------------------------------------
__global__ void __launch_bounds__(FT) gcn_pool_kernel(
    const int* __restrict__ rows, const int* __restrict__ cols,
    const float* __restrict__ vals, const __half* __restrict__ hidden,
    const unsigned short* __restrict__ node_seg,
    float* __restrict__ partials, int nE) {
    __shared__ unsigned hist[NG];
    __shared__ unsigned cursor[NG];
    __shared__ unsigned wsum[FT / 64];
    __shared__ unsigned wctr;
    __shared__ unsigned short raw_g[CHUNK];
    __shared__ uint2 sorted[CHUNK];

    const int t = threadIdx.x, lane = t & 63, wid = t >> 6;
    const int beg = blockIdx.x * CHUNK;
    const int cnt = min(nE - beg, CHUNK);

    for (int i = t; i < NG; i += FT) hist[i] = 0u;
    if (t == 0) wctr = 0u;
    __syncthreads();

    // ---- pass A: int4 rows stream + 4x u16 seg gather + hist atomic ----
    for (int i = t * 4; i < cnt; i += FT * 4) {
        if (i + 3 < cnt) {
            int4 r4 = *(const int4*)(rows + beg + i);
            unsigned g0 = node_seg[r4.x];
            unsigned g1 = node_seg[r4.y];
            unsigned g2 = node_seg[r4.z];
            unsigned g3 = node_seg[r4.w];
            ushort4 gw;
            gw.x = (unsigned short)g0; gw.y = (unsigned short)g1;
            gw.z = (unsigned short)g2; gw.w = (unsigned short)g3;
            *(ushort4*)(raw_g + i) = gw;
            if (g0 < NG) atomicAdd(&hist[g0], 1u);
            if (g1 < NG) atomicAdd(&hist[g1], 1u);
            if (g2 < NG) atomicAdd(&hist[g2], 1u);
            if (g3 < NG) atomicAdd(&hist[g3], 1u);
        } else {
            for (int j = i; j < cnt; ++j) {
                unsigned g = node_seg[rows[beg + j]];
                raw_g[j] = (unsigned short)g;
                if (g < NG) atomicAdd(&hist[g], 1u);
            }
        }
    }
    __syncthreads();

    // ---- block-wide exclusive scan of hist[0..NG) -> cursor ----
    unsigned v = (t < NG) ? hist[t] : 0u;
    unsigned inc = v;
#pragma unroll
    for (int d = 1; d < 64; d <<= 1) {
        unsigned u = __shfl_up(inc, d);
        if (lane >= d) inc += u;
    }
    if (lane == 63) wsum[wid] = inc;
    __syncthreads();
    if (wid == 0) {
        unsigned v2 = (lane < FT / 64) ? wsum[lane] : 0u;
        unsigned inc2 = v2;
#pragma unroll
        for (int d = 1; d < FT / 64; d <<= 1) {
            unsigned u = __shfl_up(inc2, d);
            if (lane >= d) inc2 += u;
        }
        if (lane < FT / 64) wsum[lane] = inc2 - v2;
    }
    __syncthreads();
    if (t < NG) cursor[t] = wsum[wid] + inc - v;
    __syncthreads();

    // ---- pass B: int4 cols + float4 vals streams + LDS scatter ----
    for (int i = t * 4; i < cnt; i += FT * 4) {
        if (i + 3 < cnt) {
            int4 c4 = *(const int4*)(cols + beg + i);
            float4 v4 = *(const float4*)(vals + beg + i);
            ushort4 gw = *(const ushort4*)(raw_g + i);
            if (gw.x < NG) sorted[atomicAdd(&cursor[gw.x], 1u)] =
                make_uint2((unsigned)c4.x, __float_as_uint(v4.x));
            if (gw.y < NG) sorted[atomicAdd(&cursor[gw.y], 1u)] =
                make_uint2((unsigned)c4.y, __float_as_uint(v4.y));
            if (gw.z < NG) sorted[atomicAdd(&cursor[gw.z], 1u)] =
                make_uint2((unsigned)c4.z, __float_as_uint(v4.z));
            if (gw.w < NG) sorted[atomicAdd(&cursor[gw.w], 1u)] =
                make_uint2((unsigned)c4.w, __float_as_uint(v4.w));
        } else {
            for (int j = i; j < cnt; ++j) {
                unsigned g = raw_g[j];
                if (g < NG) sorted[atomicAdd(&cursor[g], 1u)] =
                    make_uint2((unsigned)cols[beg + j],
                               __float_as_uint(vals[beg + j]));
            }
        }
    }
    __syncthreads();
    // post-B: cursor[g] = run end; run start = cursor[g] - hist[g]

    // ---- pool: quads pop graphs from dynamic queue; MLP=4 groups ----
    const int q = lane & 3;
    const unsigned choff = (unsigned)q * 4;
    unsigned g;
    if (q == 0) g = atomicAdd(&wctr, 1u);
    g = (unsigned)__shfl((int)g, lane & ~3);
    while (g < NG) {
        float a0 = 0.f, a1 = 0.f, a2 = 0.f, a3 = 0.f;
        unsigned cg = hist[g];
        if (cg) {
            unsigned rend = cursor[g];
            unsigned rbeg = rend - cg;
            for (unsigned i = rbeg; i < rend; i += 4) {
                unsigned j1 = min(i + 1, rend - 1);
                unsigned j2 = min(i + 2, rend - 1);
                unsigned j3 = min(i + 3, rend - 1);
                uint2 c0 = sorted[i],  c1 = sorted[j1];
                uint2 c2 = sorted[j2], c3 = sorted[j3];
                uint2 h0 = *(const uint2*)(hidden + (size_t)c0.x * NC + choff);
                uint2 h1 = *(const uint2*)(hidden + (size_t)c1.x * NC + choff);
                uint2 h2 = *(const uint2*)(hidden + (size_t)c2.x * NC + choff);
                uint2 h3 = *(const uint2*)(hidden + (size_t)c3.x * NC + choff);
                float v0 = __uint_as_float(c0.y);
                float v1 = (i + 1 < rend) ? __uint_as_float(c1.y) : 0.f;
                float v2 = (i + 2 < rend) ? __uint_as_float(c2.y) : 0.f;
                float v3 = (i + 3 < rend) ? __uint_as_float(c3.y) : 0.f;

                float2 f;
                f = __half22float2(*(__half2*)&h0.x);
                a0 = fmaf(v0, f.x, a0); a1 = fmaf(v0, f.y, a1);
                f = __half22float2(*(__half2*)&h0.y);
                a2 = fmaf(v0, f.x, a2); a3 = fmaf(v0, f.y, a3);
                f = __half22float2(*(__half2*)&h1.x);
                a0 = fmaf(v1, f.x, a0); a1 = fmaf(v1, f.y, a1);
                f = __half22float2(*(__half2*)&h1.y);
                a2 = fmaf(v1, f.x, a2); a3 = fmaf(v1, f.y, a3);
                f = __half22float2(*(__half2*)&h2.x);
                a0 = fmaf(v2, f.x, a0); a1 = fmaf(v2, f.y, a1);
                f = __half22float2(*(__half2*)&h2.y);
                a2 = fmaf(v2, f.x, a2); a3 = fmaf(v2, f.y, a3);
                f = __half22float2(*(__half2*)&h3.x);
                a0 = fmaf(v3, f.x, a0); a1 = fmaf(v3, f.y, a1);
                f = __half22float2(*(__half2*)&h3.y);
                a2 = fmaf(v3, f.x, a2); a3 = fmaf(v3, f.y, a3);
            }
        }
        float4* p4 = (float4*)(partials +
                               ((size_t)blockIdx.x * NG + g) * NC + choff);
        *p4 = make_float4(a0, a1, a2, a3);

        if (q == 0) g = atomicAdd(&wctr, 1u);
        g = (unsigned)__shfl((int)g, lane & ~3);
    }
}

// ---------------------------------------------------------------------------
// K4: fold partials[NBLK][NG*NC] into out; blockIdx.y picks 64 slices.
// ---------------------------------------------------------------------------
__global__ void reduce_kernel(const float* __restrict__ partials,
                              float* __restrict__ out) {
    int i = blockIdx.x * blockDim.x + threadIdx.x;
    if (i >= NG * NC) return;
    const int per = NBLK / 8;  // 64
    const float* p = partials + (size_t)(blockIdx.y * per) * (NG * NC) + i;
    float s0 = 0.f, s1 = 0.f, s2 = 0.f, s3 = 0.f;
#pragma unroll 4
    for (int k = 0; k < per; k += 4) {
        s0 += p[(size_t)(k + 0) * (NG * NC)];
        s1 += p[(size_t)(k + 1) * (NG * NC)];
        s2 += p[(size_t)(k + 2) * (NG * NC)];
        s3 += p[(size_t)(k + 3) * (NG * NC)];
    }
    atomicAdd(&out[i], (s0 + s1) + (s2 + s3));
}

extern "C" void kernel_launch(void* const* d_in, const int* in_sizes, int n_in,
                              void* d_out, int out_size, void* d_ws, size_t ws_size,
                              hipStream_t stream) {
    const float* x      = (const float*)d_in[0];
    const int*   ed_idx = (const int*)  d_in[1];
    const int*   rows   = (const int*)  d_in[2];
    const int*   cols   = (const int*)  d_in[3];
    const float* vals   = (const float*)d_in[4];
    const float* W      = (const float*)d_in[5];
    const float* b      = (const float*)d_in[6];
    float* out = (float*)d_out;

    int N  = in_sizes[0] / DIM;   // 100000
    int G  = in_sizes[1];         // 1000
    int nE = in_sizes[2];         // 3200000

    size_t off = 0;
    auto alloc = [&](size_t bytes, size_t align) {
        off = (off + align - 1) / align * align;
        size_t r = off; off += bytes; return r;
    };
    __half* hidden = (__half*)((char*)d_ws + alloc((size_t)N * NC * 2, 16));
    unsigned short* node_seg =
        (unsigned short*)((char*)d_ws + alloc((size_t)N * 2, 16));
    float* partials =
        (float*)((char*)d_ws + alloc((size_t)NBLK * NG * NC * 4, 16));
    (void)ws_size;

    (void)hipMemsetAsync(d_out, 0, (size_t)out_size * sizeof(float), stream);

    seg_kernel<<<(N + 255) / 256, 256, 0, stream>>>(ed_idx, node_seg, N, G);
    int nTiles = (N + 15) / 16;
    int hblocks = (nTiles + 3) / 4;
    hidden_kernel<<<hblocks, 256, 0, stream>>>(x, W, b, hidden, N);
    gcn_pool_kernel<<<NBLK, FT, 0, stream>>>(rows, cols, vals, hidden,
                                             node_seg, partials, nE);
    dim3 rg((NG * NC + 255) / 256, 8);
    reduce_kernel<<<rg, 256, 0, stream>>>(partials, out);
}